// Round 1
// baseline (407.976 us; speedup 1.0000x reference)
//
#include <hip/hip_runtime.h>
#include <math.h>

// ---------------------------------------------------------------------------
// Fused YaRN-GQA attention block, bf16 MFMA pipeline:
//   cast x -> bf16 ; transpose weights -> bf16 (N-major for gemm_bt)
//   GEMM1: q = x@Wq, kv = x@Wkv         (fp32 out)
//   normrope: RMSNorm+RoPE, pack qT[b,h,t,d] (scale folded), kT[b,g,t,d]
//   vtrans: v -> vT[b,g,d,t] bf16
//   attn: causal flash, 64x64 tiles, online softmax (exp2 units)
//   GEMM2: out = attn@Wout               (fp32 -> d_out)
// ---------------------------------------------------------------------------

typedef __attribute__((ext_vector_type(8))) short s16x8;
typedef __attribute__((ext_vector_type(4))) float f32x4;
typedef __attribute__((ext_vector_type(4))) unsigned int u32x4;

__device__ __forceinline__ unsigned short f2bf(float x) {
  union { float f; unsigned int u; } v; v.f = x;
  return (unsigned short)((v.u + 0x7FFFu + ((v.u >> 16) & 1u)) >> 16);
}

// ---------------- cast x (fp32) -> bf16, 4 elems/thread ----------------
__global__ __launch_bounds__(256) void cast_bf16_k(const float* __restrict__ in,
                                                   unsigned short* __restrict__ out) {
  int i = blockIdx.x * 256 + threadIdx.x;
  float4 v = ((const float4*)in)[i];
  unsigned long long pack = (unsigned long long)f2bf(v.x)
                          | ((unsigned long long)f2bf(v.y) << 16)
                          | ((unsigned long long)f2bf(v.z) << 32)
                          | ((unsigned long long)f2bf(v.w) << 48);
  ((unsigned long long*)out)[i] = pack;
}

// ---------------- W (RxC fp32 row-major) -> Wt (CxR bf16) ----------------
__global__ __launch_bounds__(256) void wtrans_k(const float* __restrict__ in,
                                                unsigned short* __restrict__ out,
                                                int R, int C) {
  __shared__ unsigned short lt[64][65];
  const int r0 = blockIdx.x * 64, c0 = blockIdx.y * 64;
  const int j = threadIdx.x & 63, i4 = threadIdx.x >> 6;
#pragma unroll
  for (int p = 0; p < 16; ++p) {
    int i = p * 4 + i4;
    lt[i][j] = f2bf(in[(size_t)(r0 + i) * C + c0 + j]);
  }
  __syncthreads();
#pragma unroll
  for (int p = 0; p < 16; ++p) {
    int i = p * 4 + i4;
    out[(size_t)(c0 + i) * R + r0 + j] = lt[j][i];
  }
}

// ---------------- GEMM: C[M,N] = A[M,K](bf16) @ Bt[N,K](bf16), fp32 out ----
// 128x128 tile, 4 waves (each 64x64 = 4x4 frags of 16x16x32), BK=32.
__global__ __launch_bounds__(256) void gemm_bt_k(const unsigned short* __restrict__ A,
                                                 const unsigned short* __restrict__ Bt,
                                                 float* __restrict__ C,
                                                 int M, int N, int K) {
  __shared__ alignas(16) unsigned short sA[128][40];
  __shared__ alignas(16) unsigned short sB[128][40];
  const int tid = threadIdx.x;
  const int lane = tid & 63;
  const int w = tid >> 6;
  const int wm = (w >> 1) * 64, wn = (w & 1) * 64;
  const int m0 = blockIdx.x * 128, n0 = blockIdx.y * 128;
  const int l15 = lane & 15, kfr = (lane >> 4) * 8;
  f32x4 acc[4][4];
#pragma unroll
  for (int i = 0; i < 4; ++i)
#pragma unroll
    for (int j = 0; j < 4; ++j) acc[i][j] = (f32x4){0.f, 0.f, 0.f, 0.f};
  const int lrow = tid >> 2, lcol = (tid & 3) * 8;
  const unsigned short* pA0 = A + (size_t)(m0 + lrow) * K + lcol;
  const unsigned short* pA1 = A + (size_t)(m0 + 64 + lrow) * K + lcol;
  const unsigned short* pB0 = Bt + (size_t)(n0 + lrow) * K + lcol;
  const unsigned short* pB1 = Bt + (size_t)(n0 + 64 + lrow) * K + lcol;
  for (int k0 = 0; k0 < K; k0 += 32) {
    u32x4 a0 = *(const u32x4*)(pA0 + k0);
    u32x4 a1 = *(const u32x4*)(pA1 + k0);
    u32x4 b0 = *(const u32x4*)(pB0 + k0);
    u32x4 b1 = *(const u32x4*)(pB1 + k0);
    __syncthreads();                     // protect prev iter's reads
    *(u32x4*)&sA[lrow][lcol] = a0;
    *(u32x4*)&sA[64 + lrow][lcol] = a1;
    *(u32x4*)&sB[lrow][lcol] = b0;
    *(u32x4*)&sB[64 + lrow][lcol] = b1;
    __syncthreads();
    s16x8 af[4], bfr[4];
#pragma unroll
    for (int i = 0; i < 4; ++i) af[i] = *(const s16x8*)&sA[wm + i * 16 + l15][kfr];
#pragma unroll
    for (int j = 0; j < 4; ++j) bfr[j] = *(const s16x8*)&sB[wn + j * 16 + l15][kfr];
#pragma unroll
    for (int i = 0; i < 4; ++i)
#pragma unroll
      for (int j = 0; j < 4; ++j)
        acc[i][j] = __builtin_amdgcn_mfma_f32_16x16x32_bf16(af[i], bfr[j], acc[i][j], 0, 0, 0);
  }
  const int col0 = n0 + wn + l15;
  const int row00 = m0 + wm + (lane >> 4) * 4;
#pragma unroll
  for (int i = 0; i < 4; ++i)
#pragma unroll
    for (int j = 0; j < 4; ++j)
#pragma unroll
      for (int r = 0; r < 4; ++r)
        C[(size_t)(row00 + i * 16 + r) * N + col0 + j * 16] = acc[i][j][r];
}

// ---------------- RMSNorm + RoPE + pack (one wave per 128-vec) ----------------
__global__ __launch_bounds__(256) void normrope_k(const float* __restrict__ qf,
                                                  const float* __restrict__ kvf,
                                                  const float* __restrict__ qw,
                                                  const float* __restrict__ kw,
                                                  const float* __restrict__ invf,
                                                  unsigned short* __restrict__ qT,
                                                  unsigned short* __restrict__ kT) {
  // fold attn_scale * log2(e) into q so attention can use exp2
  constexpr float FOLD =
      (float)(1.4426950408889634 / ((0.1 * 0.6931471805599453 + 1.0) * 11.313708498984761));
  int wid = blockIdx.x * 4 + (threadIdx.x >> 6);
  int lane = threadIdx.x & 63;
  const float* src; const float* wgt; unsigned short* dst;
  int t; float fold;
  if (wid < 65536) {                       // q rows: 4096 tokens * 16 heads
    int bt = wid >> 4, h = wid & 15;
    int b = bt >> 11; t = bt & 2047;
    src = qf + (size_t)bt * 2048 + h * 128;
    wgt = qw;
    dst = qT + ((size_t)(b * 16 + h) * 2048 + t) * 128;
    fold = FOLD;
  } else {                                 // k rows: 4096 tokens * 4 groups
    int id = wid - 65536;
    int bt = id >> 2, g = id & 3;
    int b = bt >> 11; t = bt & 2047;
    src = kvf + (size_t)bt * 1024 + g * 128;
    wgt = kw;
    dst = kT + ((size_t)(b * 4 + g) * 2048 + t) * 128;
    fold = 1.0f;
  }
  float2 v = ((const float2*)src)[lane];   // d = 2*lane, 2*lane+1
  float ss = v.x * v.x + v.y * v.y;
#pragma unroll
  for (int m = 32; m; m >>= 1) ss += __shfl_xor(ss, m);
  float rs = rsqrtf(ss * (1.0f / 128.0f) + 1.1920929e-07f);
  float2 wv = ((const float2*)wgt)[lane];
  float xn0 = v.x * rs * wv.x;
  float xn1 = v.y * rs * wv.y;
  // rope pairs (d, d+64): partner lives in lane^32
  float px = __shfl_xor(xn0, 32);
  float py = __shfl_xor(xn1, 32);
  float sgn = (lane < 32) ? -1.0f : 1.0f;
  int f0 = (2 * lane) & 63;
  float tf = (float)t;
  float s0, c0, s1, c1;
  sincosf(tf * invf[f0], &s0, &c0);
  sincosf(tf * invf[f0 + 1], &s1, &c1);
  float r0 = (xn0 * c0 + sgn * px * s0) * fold;
  float r1 = (xn1 * c1 + sgn * py * s1) * fold;
  unsigned int packed = (unsigned int)f2bf(r0) | ((unsigned int)f2bf(r1) << 16);
  ((unsigned int*)dst)[lane] = packed;
}

// ---------------- v (from kvf cols [512,1024)) -> vT[b,g,d,t] bf16 ----------------
__global__ __launch_bounds__(256) void vtrans_k(const float* __restrict__ kvf,
                                                unsigned short* __restrict__ vT) {
  __shared__ unsigned short lt[64][65];
  const int tt0 = blockIdx.x * 64;
  const int dd0 = blockIdx.y * 64;
  const int b = blockIdx.z >> 2, g = blockIdx.z & 3;
  const int j = threadIdx.x & 63, i4 = threadIdx.x >> 6;
  const float* src = kvf + (size_t)b * 2048 * 1024 + 512 + g * 128 + dd0;
#pragma unroll
  for (int p = 0; p < 16; ++p) {
    int i = p * 4 + i4;
    lt[i][j] = f2bf(src[(size_t)(tt0 + i) * 1024 + j]);
  }
  __syncthreads();
  unsigned short* dst = vT + ((size_t)(b * 4 + g) * 128 + dd0) * 2048 + tt0;
#pragma unroll
  for (int p = 0; p < 16; ++p) {
    int d = p * 4 + i4;
    dst[(size_t)d * 2048 + j] = lt[j][d];
  }
}

// ---------------- causal flash attention, 64x64 tiles, 4 waves ----------------
__global__ __launch_bounds__(256) void attn_k(const unsigned short* __restrict__ qT,
                                              const unsigned short* __restrict__ kT,
                                              const unsigned short* __restrict__ vT,
                                              unsigned short* __restrict__ ao) {
  __shared__ alignas(16) unsigned short sQ[64][136];
  __shared__ alignas(16) unsigned short sK[64][136];
  __shared__ alignas(16) unsigned short sVt[128][72];
  __shared__ alignas(16) unsigned short sP[64][72];
  const int tid = threadIdx.x;
  const int lane = tid & 63;
  const int w = tid >> 6;            // wave: rows w*16..w*16+15 of the Q tile
  const int l15 = lane & 15, lhi = lane >> 4;
  const int qt = blockIdx.x;
  const int b = blockIdx.y >> 4, h = blockIdx.y & 15, g = h & 3;
  const unsigned short* Qb = qT + ((size_t)(b * 16 + h) * 2048) * 128;
  const unsigned short* Kb = kT + ((size_t)(b * 4 + g) * 2048) * 128;
  const unsigned short* Vb = vT + ((size_t)(b * 4 + g) * 128) * 2048;
  {
    int r = tid >> 4, c = (tid & 15) * 8;
#pragma unroll
    for (int p = 0; p < 4; ++p)
      *(u32x4*)&sQ[p * 16 + r][c] =
          *(const u32x4*)(Qb + (size_t)(qt * 64 + p * 16 + r) * 128 + c);
  }
  f32x4 o[8];
#pragma unroll
  for (int i = 0; i < 8; ++i) o[i] = (f32x4){0.f, 0.f, 0.f, 0.f};
  float m_run[4], l_run[4];
#pragma unroll
  for (int r = 0; r < 4; ++r) { m_run[r] = -INFINITY; l_run[r] = 0.0f; }

  for (int kt = 0; kt <= qt; ++kt) {
    __syncthreads();                  // prev iter reads done (also covers sQ on kt=0)
    {
      int r = tid >> 4, c = (tid & 15) * 8;
#pragma unroll
      for (int p = 0; p < 4; ++p)
        *(u32x4*)&sK[p * 16 + r][c] =
            *(const u32x4*)(Kb + (size_t)(kt * 64 + p * 16 + r) * 128 + c);
      int r2 = tid >> 3, c2 = (tid & 7) * 8;
#pragma unroll
      for (int p = 0; p < 4; ++p)
        *(u32x4*)&sVt[p * 32 + r2][c2] =
            *(const u32x4*)(Vb + (size_t)(p * 32 + r2) * 2048 + kt * 64 + c2);
    }
    __syncthreads();
    // S = Q K^T  (16x64 per wave; scores already in exp2 units via FOLD)
    f32x4 s[4];
#pragma unroll
    for (int jn = 0; jn < 4; ++jn) s[jn] = (f32x4){0.f, 0.f, 0.f, 0.f};
#pragma unroll
    for (int ks = 0; ks < 4; ++ks) {
      s16x8 aq = *(const s16x8*)&sQ[w * 16 + l15][ks * 32 + lhi * 8];
#pragma unroll
      for (int jn = 0; jn < 4; ++jn) {
        s16x8 bk = *(const s16x8*)&sK[jn * 16 + l15][ks * 32 + lhi * 8];
        s[jn] = __builtin_amdgcn_mfma_f32_16x16x32_bf16(aq, bk, s[jn], 0, 0, 0);
      }
    }
    if (kt == qt) {                   // diagonal tile causal mask
#pragma unroll
      for (int jn = 0; jn < 4; ++jn)
#pragma unroll
        for (int r = 0; r < 4; ++r)
          if (jn * 16 + l15 > w * 16 + lhi * 4 + r) s[jn][r] = -INFINITY;
    }
    // online softmax (rows m = lhi*4+r within wave strip; 16 lanes hold the cols)
    float scale[4], p[4][4];
#pragma unroll
    for (int r = 0; r < 4; ++r) {
      float mx = fmaxf(fmaxf(s[0][r], s[1][r]), fmaxf(s[2][r], s[3][r]));
      mx = fmaxf(mx, __shfl_xor(mx, 1));
      mx = fmaxf(mx, __shfl_xor(mx, 2));
      mx = fmaxf(mx, __shfl_xor(mx, 4));
      mx = fmaxf(mx, __shfl_xor(mx, 8));
      float mnew = fmaxf(m_run[r], mx);
      scale[r] = exp2f(m_run[r] - mnew);
      m_run[r] = mnew;
      float sum = 0.f;
#pragma unroll
      for (int jn = 0; jn < 4; ++jn) {
        float pv = exp2f(s[jn][r] - mnew);
        p[jn][r] = pv;
        sum += pv;
      }
      sum += __shfl_xor(sum, 1);
      sum += __shfl_xor(sum, 2);
      sum += __shfl_xor(sum, 4);
      sum += __shfl_xor(sum, 8);
      l_run[r] = l_run[r] * scale[r] + sum;
    }
    // P -> wave-private LDS (bf16), then rescale O
#pragma unroll
    for (int jn = 0; jn < 4; ++jn)
#pragma unroll
      for (int r = 0; r < 4; ++r)
        sP[w * 16 + lhi * 4 + r][jn * 16 + l15] = f2bf(p[jn][r]);
#pragma unroll
    for (int nt = 0; nt < 8; ++nt)
#pragma unroll
      for (int r = 0; r < 4; ++r) o[nt][r] *= scale[r];
    // O += P V   (A-frag from sP rows = own wave's strip; B-frag from sVt)
#pragma unroll
    for (int ks = 0; ks < 2; ++ks) {
      s16x8 pa = *(const s16x8*)&sP[w * 16 + l15][ks * 32 + lhi * 8];
#pragma unroll
      for (int nt = 0; nt < 8; ++nt) {
        s16x8 vb = *(const s16x8*)&sVt[nt * 16 + l15][ks * 32 + lhi * 8];
        o[nt] = __builtin_amdgcn_mfma_f32_16x16x32_bf16(pa, vb, o[nt], 0, 0, 0);
      }
    }
  }
  // epilogue: normalize and store attn_out[b*T+t][h*128 + d] bf16
#pragma unroll
  for (int r = 0; r < 4; ++r) {
    float inv = 1.0f / l_run[r];
    int t = qt * 64 + w * 16 + lhi * 4 + r;
    size_t base = ((size_t)b * 2048 + t) * 2048 + h * 128;
#pragma unroll
    for (int nt = 0; nt < 8; ++nt)
      ao[base + nt * 16 + l15] = f2bf(o[nt][r] * inv);
  }
}

// ---------------------------------------------------------------------------
extern "C" void kernel_launch(void* const* d_in, const int* in_sizes, int n_in,
                              void* d_out, int out_size, void* d_ws, size_t ws_size,
                              hipStream_t stream) {
  (void)in_sizes; (void)n_in; (void)out_size; (void)ws_size;
  const float* x    = (const float*)d_in[0];
  const float* Wq   = (const float*)d_in[1];
  const float* Wkv  = (const float*)d_in[2];
  const float* Wout = (const float*)d_in[3];
  const float* qw   = (const float*)d_in[4];
  const float* kw   = (const float*)d_in[5];
  const float* invf = (const float*)d_in[6];
  float* out = (float*)d_out;

  char* ws = (char*)d_ws;
  size_t off = 0;
  auto alloc = [&](size_t bytes) -> void* {
    void* p = ws + off; off += (bytes + 255) & ~(size_t)255; return p;
  };
  unsigned short* xb   = (unsigned short*)alloc((size_t)4096 * 2048 * 2);
  unsigned short* wqt  = (unsigned short*)alloc((size_t)2048 * 2048 * 2);
  unsigned short* wkvt = (unsigned short*)alloc((size_t)1024 * 2048 * 2);
  unsigned short* wot  = (unsigned short*)alloc((size_t)2048 * 2048 * 2);
  float* qf  = (float*)alloc((size_t)4096 * 2048 * 4);
  float* kvf = (float*)alloc((size_t)4096 * 1024 * 4);
  unsigned short* qT = (unsigned short*)alloc((size_t)2 * 16 * 2048 * 128 * 2);
  unsigned short* kT = (unsigned short*)alloc((size_t)2 * 4 * 2048 * 128 * 2);
  unsigned short* vT = (unsigned short*)alloc((size_t)2 * 4 * 128 * 2048 * 2);
  unsigned short* ao = (unsigned short*)alloc((size_t)4096 * 2048 * 2);

  cast_bf16_k<<<8192, 256, 0, stream>>>(x, xb);
  wtrans_k<<<dim3(32, 32), 256, 0, stream>>>(Wq, wqt, 2048, 2048);
  wtrans_k<<<dim3(32, 16), 256, 0, stream>>>(Wkv, wkvt, 2048, 1024);
  wtrans_k<<<dim3(32, 32), 256, 0, stream>>>(Wout, wot, 2048, 2048);
  gemm_bt_k<<<dim3(32, 16), 256, 0, stream>>>(xb, wqt, qf, 4096, 2048, 2048);
  gemm_bt_k<<<dim3(32, 8), 256, 0, stream>>>(xb, wkvt, kvf, 4096, 1024, 2048);
  normrope_k<<<20480, 256, 0, stream>>>(qf, kvf, qw, kw, invf, qT, kT);
  vtrans_k<<<dim3(32, 2, 8), 256, 0, stream>>>(kvf, vT);
  attn_k<<<dim3(32, 32), 256, 0, stream>>>(qT, kT, vT, ao);
  gemm_bt_k<<<dim3(32, 16), 256, 0, stream>>>(ao, wot, out, 4096, 2048, 2048);
}

// Round 2
// 282.756 us; speedup vs baseline: 1.4429x; 1.4429x over previous
//
#include <hip/hip_runtime.h>
#include <math.h>

// ---------------------------------------------------------------------------
// Fused YaRN-GQA attention block, bf16 MFMA pipeline.
// R2 changes:
//  - attn: swapped QK^T (mfma(K,Q)) -> per-lane P rows, in-register softmax,
//    lane-local P->PV packing via k-permutation pi (V pre-permuted in vtrans),
//    Q in registers, qt-pairing (qi, 31-qi) for load balance, async-stage K/V.
//  - gemm: m97 structure (global_load_lds width=16, linear LDS, 2-barrier).
// ---------------------------------------------------------------------------

typedef __attribute__((ext_vector_type(8))) short s16x8;
typedef __attribute__((ext_vector_type(4))) float f32x4;
typedef __attribute__((ext_vector_type(4))) unsigned int u32x4;

__device__ __forceinline__ unsigned short f2bf(float x) {
  union { float f; unsigned int u; } v; v.f = x;
  return (unsigned short)((v.u + 0x7FFFu + ((v.u >> 16) & 1u)) >> 16);
}

#define GLD_LDS16(g, l)                                            \
  __builtin_amdgcn_global_load_lds(                                \
      (const __attribute__((address_space(1))) void*)(g),          \
      (__attribute__((address_space(3))) void*)(l), 16, 0, 0)

// ---------------- cast x (fp32) -> bf16, 4 elems/thread ----------------
__global__ __launch_bounds__(256) void cast_bf16_k(const float* __restrict__ in,
                                                   unsigned short* __restrict__ out) {
  int i = blockIdx.x * 256 + threadIdx.x;
  float4 v = ((const float4*)in)[i];
  unsigned long long pack = (unsigned long long)f2bf(v.x)
                          | ((unsigned long long)f2bf(v.y) << 16)
                          | ((unsigned long long)f2bf(v.z) << 32)
                          | ((unsigned long long)f2bf(v.w) << 48);
  ((unsigned long long*)out)[i] = pack;
}

// ---------------- W (RxC fp32 row-major) -> Wt (CxR bf16) ----------------
__global__ __launch_bounds__(256) void wtrans_k(const float* __restrict__ in,
                                                unsigned short* __restrict__ out,
                                                int R, int C) {
  __shared__ unsigned short lt[64][65];
  const int r0 = blockIdx.x * 64, c0 = blockIdx.y * 64;
  const int j = threadIdx.x & 63, i4 = threadIdx.x >> 6;
#pragma unroll
  for (int p = 0; p < 16; ++p) {
    int i = p * 4 + i4;
    lt[i][j] = f2bf(in[(size_t)(r0 + i) * C + c0 + j]);
  }
  __syncthreads();
#pragma unroll
  for (int p = 0; p < 16; ++p) {
    int i = p * 4 + i4;
    out[(size_t)(c0 + i) * R + r0 + j] = lt[j][i];
  }
}

// ---------------- GEMM (m97): C[M,N] = A[M,K] @ Bt[N,K], bf16 in, fp32 out --
// 128x128 tile, 4 waves, BK=32, global_load_lds width-16 staging, linear LDS.
__global__ __launch_bounds__(256) void gemm_bt_k(const unsigned short* __restrict__ A,
                                                 const unsigned short* __restrict__ Bt,
                                                 float* __restrict__ C,
                                                 int M, int N, int K) {
  __shared__ alignas(16) unsigned short sA[128][32];
  __shared__ alignas(16) unsigned short sB[128][32];
  const int tid = threadIdx.x;
  const int lane = tid & 63;
  const int w = tid >> 6;
  const int wm = (w >> 1) * 64, wn = (w & 1) * 64;
  const int m0 = blockIdx.x * 128, n0 = blockIdx.y * 128;
  const int l15 = lane & 15, kfr = (lane >> 4) * 8;
  f32x4 acc[4][4];
#pragma unroll
  for (int i = 0; i < 4; ++i)
#pragma unroll
    for (int j = 0; j < 4; ++j) acc[i][j] = (f32x4){0.f, 0.f, 0.f, 0.f};
  // global source: lane covers row tid>>2, col (tid&3)*8 (matches linear LDS fill)
  const int row = tid >> 2, col = (tid & 3) * 8;
  const unsigned short* gA0 = A + (size_t)(m0 + row) * K + col;
  const unsigned short* gA1 = A + (size_t)(m0 + 64 + row) * K + col;
  const unsigned short* gB0 = Bt + (size_t)(n0 + row) * K + col;
  const unsigned short* gB1 = Bt + (size_t)(n0 + 64 + row) * K + col;
  char* ldsA = (char*)&sA[0][0] + w * 1024;   // wave-uniform base; HW adds lane*16
  char* ldsB = (char*)&sB[0][0] + w * 1024;
  for (int k0 = 0; k0 < K; k0 += 32) {
    __syncthreads();                 // prev iter's frag reads done
    GLD_LDS16(gA0 + k0, ldsA);
    GLD_LDS16(gA1 + k0, ldsA + 4096);
    GLD_LDS16(gB0 + k0, ldsB);
    GLD_LDS16(gB1 + k0, ldsB + 4096);
    __syncthreads();                 // compiler drains vmcnt before barrier
    s16x8 af[4], bfr[4];
#pragma unroll
    for (int i = 0; i < 4; ++i) af[i] = *(const s16x8*)&sA[wm + i * 16 + l15][kfr];
#pragma unroll
    for (int j = 0; j < 4; ++j) bfr[j] = *(const s16x8*)&sB[wn + j * 16 + l15][kfr];
#pragma unroll
    for (int i = 0; i < 4; ++i)
#pragma unroll
      for (int j = 0; j < 4; ++j)
        acc[i][j] = __builtin_amdgcn_mfma_f32_16x16x32_bf16(af[i], bfr[j], acc[i][j], 0, 0, 0);
  }
  const int col0 = n0 + wn + l15;
  const int row00 = m0 + wm + (lane >> 4) * 4;
#pragma unroll
  for (int i = 0; i < 4; ++i)
#pragma unroll
    for (int j = 0; j < 4; ++j)
#pragma unroll
      for (int r = 0; r < 4; ++r)
        C[(size_t)(row00 + i * 16 + r) * N + col0 + j * 16] = acc[i][j][r];
}

// ---------------- RMSNorm + RoPE + pack (one wave per 128-vec) ----------------
__global__ __launch_bounds__(256) void normrope_k(const float* __restrict__ qf,
                                                  const float* __restrict__ kvf,
                                                  const float* __restrict__ qw,
                                                  const float* __restrict__ kw,
                                                  const float* __restrict__ invf,
                                                  unsigned short* __restrict__ qT,
                                                  unsigned short* __restrict__ kT) {
  constexpr float FOLD =
      (float)(1.4426950408889634 / ((0.1 * 0.6931471805599453 + 1.0) * 11.313708498984761));
  int wid = blockIdx.x * 4 + (threadIdx.x >> 6);
  int lane = threadIdx.x & 63;
  const float* src; const float* wgt; unsigned short* dst;
  int t; float fold;
  if (wid < 65536) {
    int bt = wid >> 4, h = wid & 15;
    int b = bt >> 11; t = bt & 2047;
    src = qf + (size_t)bt * 2048 + h * 128;
    wgt = qw;
    dst = qT + ((size_t)(b * 16 + h) * 2048 + t) * 128;
    fold = FOLD;
  } else {
    int id = wid - 65536;
    int bt = id >> 2, g = id & 3;
    int b = bt >> 11; t = bt & 2047;
    src = kvf + (size_t)bt * 1024 + g * 128;
    wgt = kw;
    dst = kT + ((size_t)(b * 4 + g) * 2048 + t) * 128;
    fold = 1.0f;
  }
  float2 v = ((const float2*)src)[lane];
  float ss = v.x * v.x + v.y * v.y;
#pragma unroll
  for (int m = 32; m; m >>= 1) ss += __shfl_xor(ss, m);
  float rs = rsqrtf(ss * (1.0f / 128.0f) + 1.1920929e-07f);
  float2 wv = ((const float2*)wgt)[lane];
  float xn0 = v.x * rs * wv.x;
  float xn1 = v.y * rs * wv.y;
  float px = __shfl_xor(xn0, 32);
  float py = __shfl_xor(xn1, 32);
  float sgn = (lane < 32) ? -1.0f : 1.0f;
  int f0 = (2 * lane) & 63;
  float tf = (float)t;
  float s0, c0, s1, c1;
  sincosf(tf * invf[f0], &s0, &c0);
  sincosf(tf * invf[f0 + 1], &s1, &c1);
  float r0 = (xn0 * c0 + sgn * px * s0) * fold;
  float r1 = (xn1 * c1 + sgn * py * s1) * fold;
  unsigned int packed = (unsigned int)f2bf(r0) | ((unsigned int)f2bf(r1) << 16);
  ((unsigned int*)dst)[lane] = packed;
}

// ---------------- v -> vT[b,g,d,t'] bf16, t' = pi^-1-permuted within 32-blocks --
// sigma(t) = ((t&15)>>2)*8 + ((t>>4)&1)*4 + (t&3) so that reading 8 consecutive
// t' at offset lhi*8 yields V rows pi(lhi*8+j) — matching the PV A-frag packing.
__global__ __launch_bounds__(256) void vtrans_k(const float* __restrict__ kvf,
                                                unsigned short* __restrict__ vT) {
  __shared__ unsigned short lt[64][65];
  const int tt0 = blockIdx.x * 64;
  const int dd0 = blockIdx.y * 64;
  const int b = blockIdx.z >> 2, g = blockIdx.z & 3;
  const int j = threadIdx.x & 63, i4 = threadIdx.x >> 6;
  const float* src = kvf + (size_t)b * 2048 * 1024 + 512 + g * 128 + dd0;
#pragma unroll
  for (int p = 0; p < 16; ++p) {
    int i = p * 4 + i4;
    lt[i][j] = f2bf(src[(size_t)(tt0 + i) * 1024 + j]);
  }
  __syncthreads();
  unsigned short* dst = vT + ((size_t)(b * 4 + g) * 128 + dd0) * 2048 + tt0;
  const int jp = (j & 32) | (((j & 15) >> 2) << 3) | (((j >> 4) & 1) << 2) | (j & 3);
#pragma unroll
  for (int p = 0; p < 16; ++p) {
    int d = p * 4 + i4;
    dst[(size_t)d * 2048 + jp] = lt[j][d];
  }
}

// ---------------- causal flash attention ----------------
// 4 waves * 16 q-rows; swapped QK^T: p-row per lane (qrow = lane&15).
// Block does qt=qi then qt=31-qi (33 kt-tiles total, balanced).
__global__ __launch_bounds__(256) void attn_k(const unsigned short* __restrict__ qT,
                                              const unsigned short* __restrict__ kT,
                                              const unsigned short* __restrict__ vT,
                                              unsigned short* __restrict__ ao) {
  __shared__ alignas(16) unsigned short sK[64][136];
  __shared__ alignas(16) unsigned short sVt[128][72];
  const int tid = threadIdx.x;
  const int lane = tid & 63;
  const int w = tid >> 6;
  const int l15 = lane & 15, lhi = lane >> 4;
  const int qi = blockIdx.x;               // 0..15
  const int b = blockIdx.y >> 4, h = blockIdx.y & 15, g = h & 3;
  const unsigned short* Qb = qT + ((size_t)(b * 16 + h) * 2048) * 128;
  const unsigned short* Kb = kT + ((size_t)(b * 4 + g) * 2048) * 128;
  const unsigned short* Vb = vT + ((size_t)(b * 4 + g) * 128) * 2048;
  const int kr = tid >> 4, kc = (tid & 15) * 8;   // K/Q staging coords
  const int vr = tid >> 3, vc = (tid & 7) * 8;    // V staging coords

  for (int pass = 0; pass < 2; ++pass) {
    const int qt = pass ? (31 - qi) : qi;
    __syncthreads();                       // prev pass LDS reads done
#pragma unroll
    for (int p = 0; p < 4; ++p)
      *(u32x4*)&sK[p * 16 + kr][kc] =
          *(const u32x4*)(Qb + (size_t)(qt * 64 + p * 16 + kr) * 128 + kc);
    __syncthreads();
    s16x8 qfr[4];
#pragma unroll
    for (int ks = 0; ks < 4; ++ks)
      qfr[ks] = *(const s16x8*)&sK[w * 16 + l15][ks * 32 + lhi * 8];
    // prefetch kt=0 K/V into regs
    u32x4 gk[4], gv[4];
#pragma unroll
    for (int p = 0; p < 4; ++p) {
      gk[p] = *(const u32x4*)(Kb + (size_t)(p * 16 + kr) * 128 + kc);
      gv[p] = *(const u32x4*)(Vb + (size_t)(p * 32 + vr) * 2048 + vc);
    }
    f32x4 o[8];
#pragma unroll
    for (int i = 0; i < 8; ++i) o[i] = (f32x4){0.f, 0.f, 0.f, 0.f};
    float m_run = -INFINITY, l_run = 0.f;

    for (int kt = 0; kt <= qt; ++kt) {
      __syncthreads();                     // Q-frag / prev-iter reads done
#pragma unroll
      for (int p = 0; p < 4; ++p) {
        *(u32x4*)&sK[p * 16 + kr][kc] = gk[p];
        *(u32x4*)&sVt[p * 32 + vr][vc] = gv[p];
      }
      __syncthreads();
      if (kt < qt) {                       // T14: issue next-tile loads early
#pragma unroll
        for (int p = 0; p < 4; ++p) {
          gk[p] = *(const u32x4*)(Kb + (size_t)((kt + 1) * 64 + p * 16 + kr) * 128 + kc);
          gv[p] = *(const u32x4*)(Vb + (size_t)(p * 32 + vr) * 2048 + (kt + 1) * 64 + vc);
        }
      }
      // S^T tile: s[jn][r] = S[qrow = w*16+l15][kpos = jn*16+lhi*4+r] (exp2 units)
      f32x4 s[4];
#pragma unroll
      for (int jn = 0; jn < 4; ++jn) s[jn] = (f32x4){0.f, 0.f, 0.f, 0.f};
#pragma unroll
      for (int ks = 0; ks < 4; ++ks)
#pragma unroll
        for (int jn = 0; jn < 4; ++jn) {
          s16x8 ak = *(const s16x8*)&sK[jn * 16 + l15][ks * 32 + lhi * 8];
          s[jn] = __builtin_amdgcn_mfma_f32_16x16x32_bf16(ak, qfr[ks], s[jn], 0, 0, 0);
        }
      if (kt == qt) {
#pragma unroll
        for (int jn = 0; jn < 4; ++jn)
#pragma unroll
          for (int r = 0; r < 4; ++r)
            if (jn * 16 + lhi * 4 + r > w * 16 + l15) s[jn][r] = -INFINITY;
      }
      // online softmax: row fully per-lane + 2 shfl_xor across lhi groups
      float mx = -INFINITY;
#pragma unroll
      for (int jn = 0; jn < 4; ++jn)
#pragma unroll
        for (int r = 0; r < 4; ++r) mx = fmaxf(mx, s[jn][r]);
      mx = fmaxf(mx, __shfl_xor(mx, 16));
      mx = fmaxf(mx, __shfl_xor(mx, 32));
      float mnew = fmaxf(m_run, mx);
      float scale = exp2f(m_run - mnew);
      m_run = mnew;
      float pp[4][4]; float sum = 0.f;
#pragma unroll
      for (int jn = 0; jn < 4; ++jn)
#pragma unroll
        for (int r = 0; r < 4; ++r) {
          float pv = exp2f(s[jn][r] - mnew);
          pp[jn][r] = pv; sum += pv;
        }
      sum += __shfl_xor(sum, 16);
      sum += __shfl_xor(sum, 32);
      l_run = l_run * scale + sum;
      // pack PV A-frags lane-locally (pi-permuted k order; V storage matches)
      s16x8 pa0, pa1;
#pragma unroll
      for (int r = 0; r < 4; ++r) {
        pa0[r]     = (short)f2bf(pp[0][r]);
        pa0[4 + r] = (short)f2bf(pp[1][r]);
        pa1[r]     = (short)f2bf(pp[2][r]);
        pa1[4 + r] = (short)f2bf(pp[3][r]);
      }
      // rescale O (O rows = lhi*4+r): fetch scale from the lane owning that row
      float sc_o[4];
#pragma unroll
      for (int r = 0; r < 4; ++r) sc_o[r] = __shfl(scale, lhi * 4 + r);
#pragma unroll
      for (int nt = 0; nt < 8; ++nt)
#pragma unroll
        for (int r = 0; r < 4; ++r) o[nt][r] *= sc_o[r];
      // O += P V
#pragma unroll
      for (int nt = 0; nt < 8; ++nt) {
        s16x8 vb0 = *(const s16x8*)&sVt[nt * 16 + l15][lhi * 8];
        o[nt] = __builtin_amdgcn_mfma_f32_16x16x32_bf16(pa0, vb0, o[nt], 0, 0, 0);
      }
#pragma unroll
      for (int nt = 0; nt < 8; ++nt) {
        s16x8 vb1 = *(const s16x8*)&sVt[nt * 16 + l15][32 + lhi * 8];
        o[nt] = __builtin_amdgcn_mfma_f32_16x16x32_bf16(pa1, vb1, o[nt], 0, 0, 0);
      }
    }
    // epilogue
    float inv = 1.0f / l_run;
#pragma unroll
    for (int r = 0; r < 4; ++r) {
      float invr = __shfl(inv, lhi * 4 + r);
      int t = qt * 64 + w * 16 + lhi * 4 + r;
      size_t base = ((size_t)b * 2048 + t) * 2048 + h * 128;
#pragma unroll
      for (int nt = 0; nt < 8; ++nt)
        ao[base + nt * 16 + l15] = f2bf(o[nt][r] * invr);
    }
  }
}

// ---------------------------------------------------------------------------
extern "C" void kernel_launch(void* const* d_in, const int* in_sizes, int n_in,
                              void* d_out, int out_size, void* d_ws, size_t ws_size,
                              hipStream_t stream) {
  (void)in_sizes; (void)n_in; (void)out_size; (void)ws_size;
  const float* x    = (const float*)d_in[0];
  const float* Wq   = (const float*)d_in[1];
  const float* Wkv  = (const float*)d_in[2];
  const float* Wout = (const float*)d_in[3];
  const float* qw   = (const float*)d_in[4];
  const float* kw   = (const float*)d_in[5];
  const float* invf = (const float*)d_in[6];
  float* out = (float*)d_out;

  char* ws = (char*)d_ws;
  size_t off = 0;
  auto alloc = [&](size_t bytes) -> void* {
    void* p = ws + off; off += (bytes + 255) & ~(size_t)255; return p;
  };
  unsigned short* xb   = (unsigned short*)alloc((size_t)4096 * 2048 * 2);
  unsigned short* wqt  = (unsigned short*)alloc((size_t)2048 * 2048 * 2);
  unsigned short* wkvt = (unsigned short*)alloc((size_t)1024 * 2048 * 2);
  unsigned short* wot  = (unsigned short*)alloc((size_t)2048 * 2048 * 2);
  float* qf  = (float*)alloc((size_t)4096 * 2048 * 4);
  float* kvf = (float*)alloc((size_t)4096 * 1024 * 4);
  unsigned short* qT = (unsigned short*)alloc((size_t)2 * 16 * 2048 * 128 * 2);
  unsigned short* kT = (unsigned short*)alloc((size_t)2 * 4 * 2048 * 128 * 2);
  unsigned short* vT = (unsigned short*)alloc((size_t)2 * 4 * 128 * 2048 * 2);
  unsigned short* ao = (unsigned short*)alloc((size_t)4096 * 2048 * 2);

  cast_bf16_k<<<8192, 256, 0, stream>>>(x, xb);
  wtrans_k<<<dim3(32, 32), 256, 0, stream>>>(Wq, wqt, 2048, 2048);
  wtrans_k<<<dim3(32, 16), 256, 0, stream>>>(Wkv, wkvt, 2048, 1024);
  wtrans_k<<<dim3(32, 32), 256, 0, stream>>>(Wout, wot, 2048, 2048);
  gemm_bt_k<<<dim3(32, 16), 256, 0, stream>>>(xb, wqt, qf, 4096, 2048, 2048);
  gemm_bt_k<<<dim3(32, 8), 256, 0, stream>>>(xb, wkvt, kvf, 4096, 1024, 2048);
  normrope_k<<<20480, 256, 0, stream>>>(qf, kvf, qw, kw, invf, qT, kT);
  vtrans_k<<<dim3(32, 2, 8), 256, 0, stream>>>(kvf, vT);
  attn_k<<<dim3(16, 32), 256, 0, stream>>>(qT, kT, vT, ao);
  gemm_bt_k<<<dim3(32, 16), 256, 0, stream>>>(ao, wot, out, 4096, 2048, 2048);
}